// Round 3
// baseline (596.425 us; speedup 1.0000x reference)
//
#include <hip/hip_runtime.h>
#include <hip/hip_bf16.h>

#define TDIM 2048
#define BDIM 4
#define CDIM 1024
#define HDIM 16
#define DH   64

typedef __hip_bfloat16 bf16;
typedef __attribute__((ext_vector_type(8))) short bf16x8;
typedef __attribute__((ext_vector_type(4))) short bf16x4;
typedef __attribute__((ext_vector_type(4))) float f32x4;

// async global->LDS, 16B per lane; LDS dest = wave-uniform base + lane*16
__device__ __forceinline__ void async_ld16(const bf16* g, bf16* l) {
    __builtin_amdgcn_global_load_lds(
        (const __attribute__((address_space(1))) unsigned int*)g,
        (__attribute__((address_space(3))) unsigned int*)l, 16, 0, 0);
}

__device__ __forceinline__ unsigned short bf16bits(float x) {
    bf16 b = __float2bfloat16(x);
    return *(unsigned short*)&b;
}

// 16x16x16 bf16 MFMA (k=16): verified working in round 8 (passed correctness)
__device__ __forceinline__ f32x4 mfma_16x16x16_bf16(bf16x4 a, bf16x4 b, f32x4 c) {
#if __has_builtin(__builtin_amdgcn_mfma_f32_16x16x16_bf16)
    return __builtin_amdgcn_mfma_f32_16x16x16_bf16(a, b, c, 0, 0, 0);
#elif __has_builtin(__builtin_amdgcn_mfma_f32_16x16x16bf16_1k)
    return __builtin_amdgcn_mfma_f32_16x16x16bf16_1k(a, b, c, 0, 0, 0);
#else
    asm volatile("v_mfma_f32_16x16x16_bf16 %0, %1, %2, %0"
                 : "+v"(c) : "v"(a), "v"(b));
    return c;
#endif
}

// ---------------------------------------------------------------------------
__global__ void convert_x4(const float4* __restrict__ src, ushort4* __restrict__ dst, int n4) {
    int i = blockIdx.x * blockDim.x + threadIdx.x;
    if (i >= n4) return;
    float4 v = src[i];
    ushort4 o;
    o.x = bf16bits(v.x); o.y = bf16bits(v.y);
    o.z = bf16bits(v.z); o.w = bf16bits(v.w);
    dst[i] = o;
}

__global__ void convert_biases(const float* __restrict__ b0, const float* __restrict__ b1,
                               const float* __restrict__ b2, const float* __restrict__ b3,
                               bf16* __restrict__ dst) {
    int i = blockIdx.x * blockDim.x + threadIdx.x;   // 0..4095
    int which = i >> 10, j = i & 1023;
    const float* src = (which == 0) ? b0 : (which == 1) ? b1 : (which == 2) ? b2 : b3;
    dst[i] = __float2bfloat16(src[j]);
}

// ---------------------------------------------------------------------------
// LDS-tiled transpose, fused over Wq/Wk/Wv: z = which*16 + h.
// ---------------------------------------------------------------------------
__global__ __launch_bounds__(256) void transpose_qkv_kernel(
    const float* __restrict__ Wq, const float* __restrict__ Wk, const float* __restrict__ Wv,
    bf16* __restrict__ WqT, bf16* __restrict__ WkT, bf16* __restrict__ WvT) {
    __shared__ float tile[64][65];
    const int which = blockIdx.z >> 4, h = blockIdx.z & 15;
    const float* W  = ((which == 0) ? Wq  : (which == 1) ? Wk  : Wv)  + (size_t)h * CDIM * DH;
    bf16*        WT = ((which == 0) ? WqT : (which == 1) ? WkT : WvT) + (size_t)h * CDIM * DH;
    const int c0 = blockIdx.x * 64;
    for (int it = 0; it < 16; it++) {
        int e = it * 256 + threadIdx.x;
        int r = e >> 6, col = e & 63;
        tile[r][col] = W[(size_t)(c0 + r) * DH + col];
    }
    __syncthreads();
    for (int it = 0; it < 16; it++) {
        int e = it * 256 + threadIdx.x;
        int r = e >> 6, col = e & 63;
        WT[(size_t)r * CDIM + c0 + col] = __float2bfloat16(tile[col][r]);
    }
}

__global__ __launch_bounds__(256) void transpose_wo_kernel(
    const float* __restrict__ W, bf16* __restrict__ WT) {
    __shared__ float tile[64][65];
    const int c0 = blockIdx.x * 64, d0 = blockIdx.y * 64;
    for (int it = 0; it < 16; it++) {
        int e = it * 256 + threadIdx.x;
        int r = e >> 6, col = e & 63;
        tile[r][col] = W[(size_t)(c0 + r) * CDIM + d0 + col];
    }
    __syncthreads();
    for (int it = 0; it < 16; it++) {
        int e = it * 256 + threadIdx.x;
        int r = e >> 6, col = e & 63;
        WT[(size_t)(d0 + r) * CDIM + c0 + col] = __float2bfloat16(tile[col][r]);
    }
}

// V [bh][t][d] -> Vt [bh][d][t], 64x64 bf16 tiles
__global__ __launch_bounds__(256) void transpose_v_kernel(
    const bf16* __restrict__ V, bf16* __restrict__ Vt) {
    __shared__ unsigned short tile[64][65];
    const int bh = blockIdx.y, t0 = blockIdx.x * 64;
    const unsigned short* Vp  = (const unsigned short*)V + ((size_t)bh * TDIM + t0) * DH;
    unsigned short*       Vtp = (unsigned short*)Vt + (size_t)bh * DH * TDIM;
    for (int it = 0; it < 16; it++) {
        int e = it * 256 + threadIdx.x;
        int r = e >> 6, c = e & 63;
        tile[r][c] = Vp[(size_t)r * DH + c];
    }
    __syncthreads();
    for (int it = 0; it < 16; it++) {
        int e = it * 256 + threadIdx.x;
        int r = e >> 6, c = e & 63;
        Vtp[(size_t)r * TDIM + t0 + c] = tile[c][r];
    }
}

// ---------------------------------------------------------------------------
// 128x128 MFMA GEMM with global_load_lds staging (m97 pattern).
// QKV variant: z selects weight/bias/output; Q pre-scaled by 1/32.
// ---------------------------------------------------------------------------
__global__ __launch_bounds__(256) void proj_qkv_kernel(
    const bf16* __restrict__ X,
    const bf16* __restrict__ WqT, const bf16* __restrict__ WkT, const bf16* __restrict__ WvT,
    const bf16* __restrict__ bq,  const bf16* __restrict__ bk,  const bf16* __restrict__ bvv,
    bf16* __restrict__ Qo, bf16* __restrict__ Ko, bf16* __restrict__ Vo)
{
    const int z = blockIdx.z;
    const bf16* Bt   = (z == 0) ? WqT : (z == 1) ? WkT : WvT;
    const bf16* bias = (z == 0) ? bq  : (z == 1) ? bk  : bvv;

    __shared__ __align__(16) bf16 As[128 * 32];
    __shared__ __align__(16) bf16 Bs[128 * 32];

    const int tid  = threadIdx.x;
    const int lane = tid & 63;
    const int wave = tid >> 6;
    const int wr = wave >> 1, wc = wave & 1;
    const int l15 = lane & 15, quad = lane >> 4;

    const int blockM = blockIdx.y * 128;
    const int blockN = blockIdx.x * 128;

    f32x4 acc[4][4];
    for (int i = 0; i < 4; i++)
        for (int j = 0; j < 4; j++)
            acc[i][j] = (f32x4){0.f, 0.f, 0.f, 0.f};

    const int srow = lane >> 2, scol = (lane & 3) * 8;
    for (int k0 = 0; k0 < CDIM; k0 += 32) {
        for (int cc = 0; cc < 2; cc++) {
            int chunk = wave * 2 + cc;
            int row = chunk * 16 + srow;
            async_ld16(&X [(size_t)(blockM + row) * CDIM + k0 + scol], &As[chunk * 512]);
            async_ld16(&Bt[(size_t)(blockN + row) * CDIM + k0 + scol], &Bs[chunk * 512]);
        }
        __syncthreads();

        bf16x8 af[4], bfr[4];
        for (int mi = 0; mi < 4; mi++)
            af[mi] = *(const bf16x8*)&As[(wr * 64 + mi * 16 + l15) * 32 + quad * 8];
        for (int ni = 0; ni < 4; ni++)
            bfr[ni] = *(const bf16x8*)&Bs[(wc * 64 + ni * 16 + l15) * 32 + quad * 8];

        for (int mi = 0; mi < 4; mi++)
            for (int ni = 0; ni < 4; ni++)
                acc[mi][ni] = __builtin_amdgcn_mfma_f32_16x16x32_bf16(
                    af[mi], bfr[ni], acc[mi][ni], 0, 0, 0);
        __syncthreads();
    }

    for (int mi = 0; mi < 4; mi++) {
        int mbase = blockM + wr * 64 + mi * 16 + quad * 4;
        for (int ni = 0; ni < 4; ni++) {
            int n = blockN + wc * 64 + ni * 16 + l15;
            float bval = __bfloat162float(bias[n]);
            int h = n >> 6, d = n & 63;
            for (int r = 0; r < 4; r++) {
                int mm = mbase + r;
                int b = mm >> 11, t = mm & 2047;
                float val = acc[mi][ni][r] + bval;
                size_t idx = (((size_t)b * HDIM + h) * TDIM + t) * DH + d;
                if (z == 0)      Qo[idx] = __float2bfloat16(val * 0.03125f);
                else if (z == 1) Ko[idx] = __float2bfloat16(val);
                else             Vo[idx] = __float2bfloat16(val);
            }
        }
    }
}

// ---------------------------------------------------------------------------
// Output projection: Y[M,K] @ WoT[N,K]^T + bo -> fp32 Out
// ---------------------------------------------------------------------------
__global__ __launch_bounds__(256) void proj_out_kernel(
    const bf16* __restrict__ X, const bf16* __restrict__ Bt,
    const bf16* __restrict__ bias, float* __restrict__ Out)
{
    __shared__ __align__(16) bf16 As[128 * 32];
    __shared__ __align__(16) bf16 Bs[128 * 32];

    const int tid  = threadIdx.x;
    const int lane = tid & 63;
    const int wave = tid >> 6;
    const int wr = wave >> 1, wc = wave & 1;
    const int l15 = lane & 15, quad = lane >> 4;

    const int blockM = blockIdx.y * 128;
    const int blockN = blockIdx.x * 128;

    f32x4 acc[4][4];
    for (int i = 0; i < 4; i++)
        for (int j = 0; j < 4; j++)
            acc[i][j] = (f32x4){0.f, 0.f, 0.f, 0.f};

    const int srow = lane >> 2, scol = (lane & 3) * 8;
    for (int k0 = 0; k0 < CDIM; k0 += 32) {
        for (int cc = 0; cc < 2; cc++) {
            int chunk = wave * 2 + cc;
            int row = chunk * 16 + srow;
            async_ld16(&X [(size_t)(blockM + row) * CDIM + k0 + scol], &As[chunk * 512]);
            async_ld16(&Bt[(size_t)(blockN + row) * CDIM + k0 + scol], &Bs[chunk * 512]);
        }
        __syncthreads();

        bf16x8 af[4], bfr[4];
        for (int mi = 0; mi < 4; mi++)
            af[mi] = *(const bf16x8*)&As[(wr * 64 + mi * 16 + l15) * 32 + quad * 8];
        for (int ni = 0; ni < 4; ni++)
            bfr[ni] = *(const bf16x8*)&Bs[(wc * 64 + ni * 16 + l15) * 32 + quad * 8];

        for (int mi = 0; mi < 4; mi++)
            for (int ni = 0; ni < 4; ni++)
                acc[mi][ni] = __builtin_amdgcn_mfma_f32_16x16x32_bf16(
                    af[mi], bfr[ni], acc[mi][ni], 0, 0, 0);
        __syncthreads();
    }

    for (int mi = 0; mi < 4; mi++) {
        int mbase = blockM + wr * 64 + mi * 16 + quad * 4;
        for (int ni = 0; ni < 4; ni++) {
            int n = blockN + wc * 64 + ni * 16 + l15;
            float bval = __bfloat162float(bias[n]);
            for (int r = 0; r < 4; r++)
                Out[(size_t)(mbase + r) * CDIM + n] = acc[mi][ni][r] + bval;
        }
    }
}

// ---------------------------------------------------------------------------
// Flash attention, causal.  64-q tiles, 4 waves (256 thr), P-in-registers.
// Round-0 structure (proven 97.5us) with the g-group loop removed and grid.x
// doubled to 32: 2048 blocks = 8 blocks/CU (LDS 18.4KB -> 8 fit) x 4 waves
// = 32 waves/CU ceiling (100%) vs round-0's 50% grid cap.  Per-thread live
// state halves (one q-group: o[4]+qf+kreg/vreg ~= 45 VGPR peak) so
// __launch_bounds__(256,8) fits 64 VGPR WITHOUT the spills that killed the
// round-1 512-thread variant (VGPR 32 + 98MB scratch writes).
// Each wave owns q rows qBase + wave*16 + l15.  S^T = K.Q^T exits QK in
// [key=quad*4+r][q=l15] layout == B-operand of 16x16x16 MFMA -> exp in regs
// feeds PV directly, NO LDS round-trip for P.  Diag masking on kt==qT only.
// ---------------------------------------------------------------------------
__global__ __launch_bounds__(256, 8) void attn_kernel(
    const bf16* __restrict__ Q, const bf16* __restrict__ Kb,
    const bf16* __restrict__ Vt, bf16* __restrict__ Y)
{
    const int bh    = blockIdx.y;
    const int qT    = (int)gridDim.x - 1 - blockIdx.x;   // 0..31, heavy first
    const int qBase = qT * 64;
    const int tid  = threadIdx.x;
    const int lane = tid & 63, wave = tid >> 6;          // wave 0..3
    const int l15 = lane & 15, quad = lane >> 4;

    __shared__ __align__(16) bf16 Ks[64 * 72];       // [key][dh]
    __shared__ __align__(16) bf16 Vs[64 * 72];       // [dh][key]

    // Q B-fragments: this wave's 16 q rows
    const size_t qrow = (size_t)bh * TDIM + qBase + wave * 16 + l15;
    const bf16x8 qf0 = *(const bf16x8*)&Q[qrow * DH + quad * 8];
    const bf16x8 qf1 = *(const bf16x8*)&Q[qrow * DH + 32 + quad * 8];

    // O^T accumulators: o[mt][r] -> d = mt*16+quad*4+r, q = l15
    f32x4 o[4];
    for (int mt = 0; mt < 4; mt++) o[mt] = (f32x4){0.f, 0.f, 0.f, 0.f};
    float lsum = 0.f;

    // staging coords: 256 threads x 2 chunks x 8 bf16 = 64x64 tile per array
    const int r0 = tid >> 3, kc0 = (tid & 7) * 8;

    const int nkt  = qT + 1;
    const int qloc = wave * 16 + l15;    // q offset within this 64-q tile

    uint4 kreg0 = *(const uint4*)&Kb[((size_t)bh * TDIM + r0) * DH + kc0];
    uint4 kreg1 = *(const uint4*)&Kb[((size_t)bh * TDIM + r0 + 32) * DH + kc0];
    uint4 vreg0 = *(const uint4*)&Vt[((size_t)bh * DH + r0) * TDIM + kc0];
    uint4 vreg1 = *(const uint4*)&Vt[((size_t)bh * DH + r0 + 32) * TDIM + kc0];

    for (int kt = 0; kt < nkt; kt++) {
        *(uint4*)&Ks[r0 * 72 + kc0]        = kreg0;
        *(uint4*)&Ks[(r0 + 32) * 72 + kc0] = kreg1;
        *(uint4*)&Vs[r0 * 72 + kc0]        = vreg0;
        *(uint4*)&Vs[(r0 + 32) * 72 + kc0] = vreg1;
        __syncthreads();

        if (kt + 1 < nkt) {
            const int nb = (kt + 1) * 64;
            kreg0 = *(const uint4*)&Kb[((size_t)bh * TDIM + nb + r0) * DH + kc0];
            kreg1 = *(const uint4*)&Kb[((size_t)bh * TDIM + nb + r0 + 32) * DH + kc0];
            vreg0 = *(const uint4*)&Vt[((size_t)bh * DH + r0) * TDIM + nb + kc0];
            vreg1 = *(const uint4*)&Vt[((size_t)bh * DH + r0 + 32) * TDIM + nb + kc0];
        }

        const bool diag = (kt == qT);
        for (int nt = 0; nt < 4; nt++) {
            // K A-frag for this 16-key chunk
            bf16x8 kf0 = *(const bf16x8*)&Ks[(nt * 16 + l15) * 72 + quad * 8];
            bf16x8 kf1 = *(const bf16x8*)&Ks[(nt * 16 + l15) * 72 + 32 + quad * 8];
            // V A-frags (16x16x16): A[m=d mt*16+l15][k=key nt*16+quad*4+j]
            bf16x4 vA[4];
            for (int mt = 0; mt < 4; mt++)
                vA[mt] = *(const bf16x4*)&Vs[(mt * 16 + l15) * 72 + nt * 16 + quad * 4];

            f32x4 s = (f32x4){0.f, 0.f, 0.f, 0.f};
            s = __builtin_amdgcn_mfma_f32_16x16x32_bf16(kf0, qf0, s, 0, 0, 0);
            s = __builtin_amdgcn_mfma_f32_16x16x32_bf16(kf1, qf1, s, 0, 0, 0);

            bf16x4 pb;
            for (int r = 0; r < 4; r++) {
                float pe = __expf(s[r]);
                if (diag && (nt * 16 + quad * 4 + r > qloc)) pe = 0.f;
                lsum += pe;
                pb[r] = (short)bf16bits(pe);
            }
            for (int mt = 0; mt < 4; mt++)
                o[mt] = mfma_16x16x16_bf16(vA[mt], pb, o[mt]);
        }
        __syncthreads();
    }

    // ---- epilogue: normalize, per-wave LDS transpose, coalesced store ----
    float v = lsum;
    v += __shfl_xor(v, 16, 64);
    v += __shfl_xor(v, 32, 64);
    const float inv = 1.0f / v;

    // o -> LDS wave-private slice [q=l15 row][d col]  (reuse Ks)
    unsigned short* sm = (unsigned short*)Ks;
    for (int mt = 0; mt < 4; mt++) {
        unsigned short pk[4];
        for (int r = 0; r < 4; r++) pk[r] = bf16bits(o[mt][r] * inv);
        *(ushort4*)&sm[(wave * 16 + l15) * 72 + mt * 16 + quad * 4] = *(ushort4*)pk;
    }
    // same-wave readback, coalesced global store
    const int b = bh >> 4, h = bh & 15;
    const int qq = lane >> 2, part = lane & 3;
    const int t = qBase + wave * 16 + qq;
    uint4 c0 = *(const uint4*)&sm[(wave * 16 + qq) * 72 + part * 16];
    uint4 c1 = *(const uint4*)&sm[(wave * 16 + qq) * 72 + part * 16 + 8];
    *(uint4*)&Y[((size_t)b * TDIM + t) * CDIM + h * DH + part * 16]     = c0;
    *(uint4*)&Y[((size_t)b * TDIM + t) * CDIM + h * DH + part * 16 + 8] = c1;
}

// ---------------------------------------------------------------------------
extern "C" void kernel_launch(void* const* d_in, const int* in_sizes, int n_in,
                              void* d_out, int out_size, void* d_ws, size_t ws_size,
                              hipStream_t stream) {
    (void)in_sizes; (void)n_in; (void)out_size; (void)ws_size;

    char* ws = (char*)d_ws;
    const size_t SZ_BHTD = (size_t)BDIM * HDIM * TDIM * DH * sizeof(bf16);  // 16 MiB
    const size_t SZ_W    = (size_t)HDIM * CDIM * DH * sizeof(bf16);         // 2 MiB
    bf16* Qb  = (bf16*)(ws);
    bf16* Kb  = (bf16*)(ws + SZ_BHTD);
    bf16* Vt  = (bf16*)(ws + 2 * SZ_BHTD);
    bf16* Y   = (bf16*)(ws + 3 * SZ_BHTD);
    bf16* WqT = (bf16*)(ws + 4 * SZ_BHTD);
    bf16* WkT = (bf16*)(ws + 4 * SZ_BHTD + SZ_W);
    bf16* WvT = (bf16*)(ws + 4 * SZ_BHTD + 2 * SZ_W);
    bf16* WoT = (bf16*)(ws + 4 * SZ_BHTD + 3 * SZ_W);
    bf16* xC  = (bf16*)(ws + 4 * SZ_BHTD + 4 * SZ_W);                       // 16 MiB
    bf16* bqC = (bf16*)(ws + 5 * SZ_BHTD + 4 * SZ_W);
    bf16* bkC = bqC + 1024;
    bf16* bvC = bqC + 2048;
    bf16* boC = bqC + 3072;
    bf16* Vb  = (bf16*)d_out;   // scratch: V [bh][t][d] lives in d_out until proj_out

    const int nX4 = (BDIM * TDIM * CDIM) / 4;
    convert_x4<<<nX4 / 256, 256, 0, stream>>>((const float4*)d_in[0], (ushort4*)xC, nX4);
    convert_biases<<<16, 256, 0, stream>>>((const float*)d_in[2], (const float*)d_in[4],
                                           (const float*)d_in[6], (const float*)d_in[8], bqC);

    transpose_qkv_kernel<<<dim3(CDIM / 64, 1, 48), 256, 0, stream>>>(
        (const float*)d_in[1], (const float*)d_in[3], (const float*)d_in[5], WqT, WkT, WvT);
    transpose_wo_kernel<<<dim3(CDIM / 64, CDIM / 64), 256, 0, stream>>>(
        (const float*)d_in[7], WoT);

    dim3 gq(CDIM / 128, (BDIM * TDIM) / 128, 3);
    proj_qkv_kernel<<<gq, 256, 0, stream>>>(xC, WqT, WkT, WvT, bqC, bkC, bvC, Qb, Kb, Vb);

    transpose_v_kernel<<<dim3(TDIM / 64, BDIM * HDIM), 256, 0, stream>>>(Vb, Vt);

    attn_kernel<<<dim3(TDIM / 64, BDIM * HDIM), 256, 0, stream>>>(Qb, Kb, Vt, Y);

    proj_out_kernel<<<dim3(CDIM / 128, (BDIM * TDIM) / 128), 256, 0, stream>>>(
        Y, WoT, boC, (float*)d_out);
}

// Round 4
// 327.806 us; speedup vs baseline: 1.8194x; 1.8194x over previous
//
#include <hip/hip_runtime.h>
#include <hip/hip_bf16.h>

#define TDIM 2048
#define BDIM 4
#define CDIM 1024
#define HDIM 16
#define DH   64

typedef __hip_bfloat16 bf16;
typedef __attribute__((ext_vector_type(8))) short bf16x8;
typedef __attribute__((ext_vector_type(4))) short bf16x4;
typedef __attribute__((ext_vector_type(4))) float f32x4;

// async global->LDS, 16B per lane; LDS dest = wave-uniform base + lane*16
__device__ __forceinline__ void async_ld16(const bf16* g, bf16* l) {
    __builtin_amdgcn_global_load_lds(
        (const __attribute__((address_space(1))) unsigned int*)g,
        (__attribute__((address_space(3))) unsigned int*)l, 16, 0, 0);
}

__device__ __forceinline__ unsigned short bf16bits(float x) {
    bf16 b = __float2bfloat16(x);
    return *(unsigned short*)&b;
}

// 16x16x16 bf16 MFMA (k=16): verified working in round 8 (passed correctness)
__device__ __forceinline__ f32x4 mfma_16x16x16_bf16(bf16x4 a, bf16x4 b, f32x4 c) {
#if __has_builtin(__builtin_amdgcn_mfma_f32_16x16x16_bf16)
    return __builtin_amdgcn_mfma_f32_16x16x16_bf16(a, b, c, 0, 0, 0);
#elif __has_builtin(__builtin_amdgcn_mfma_f32_16x16x16bf16_1k)
    return __builtin_amdgcn_mfma_f32_16x16x16bf16_1k(a, b, c, 0, 0, 0);
#else
    asm volatile("v_mfma_f32_16x16x16_bf16 %0, %1, %2, %0"
                 : "+v"(c) : "v"(a), "v"(b));
    return c;
#endif
}

// ---------------------------------------------------------------------------
__global__ void convert_x4(const float4* __restrict__ src, ushort4* __restrict__ dst, int n4) {
    int i = blockIdx.x * blockDim.x + threadIdx.x;
    if (i >= n4) return;
    float4 v = src[i];
    ushort4 o;
    o.x = bf16bits(v.x); o.y = bf16bits(v.y);
    o.z = bf16bits(v.z); o.w = bf16bits(v.w);
    dst[i] = o;
}

__global__ void convert_biases(const float* __restrict__ b0, const float* __restrict__ b1,
                               const float* __restrict__ b2, const float* __restrict__ b3,
                               bf16* __restrict__ dst) {
    int i = blockIdx.x * blockDim.x + threadIdx.x;   // 0..4095
    int which = i >> 10, j = i & 1023;
    const float* src = (which == 0) ? b0 : (which == 1) ? b1 : (which == 2) ? b2 : b3;
    dst[i] = __float2bfloat16(src[j]);
}

// ---------------------------------------------------------------------------
// LDS-tiled transpose, fused over Wq/Wk/Wv: z = which*16 + h.
// ---------------------------------------------------------------------------
__global__ __launch_bounds__(256) void transpose_qkv_kernel(
    const float* __restrict__ Wq, const float* __restrict__ Wk, const float* __restrict__ Wv,
    bf16* __restrict__ WqT, bf16* __restrict__ WkT, bf16* __restrict__ WvT) {
    __shared__ float tile[64][65];
    const int which = blockIdx.z >> 4, h = blockIdx.z & 15;
    const float* W  = ((which == 0) ? Wq  : (which == 1) ? Wk  : Wv)  + (size_t)h * CDIM * DH;
    bf16*        WT = ((which == 0) ? WqT : (which == 1) ? WkT : WvT) + (size_t)h * CDIM * DH;
    const int c0 = blockIdx.x * 64;
    for (int it = 0; it < 16; it++) {
        int e = it * 256 + threadIdx.x;
        int r = e >> 6, col = e & 63;
        tile[r][col] = W[(size_t)(c0 + r) * DH + col];
    }
    __syncthreads();
    for (int it = 0; it < 16; it++) {
        int e = it * 256 + threadIdx.x;
        int r = e >> 6, col = e & 63;
        WT[(size_t)r * CDIM + c0 + col] = __float2bfloat16(tile[col][r]);
    }
}

__global__ __launch_bounds__(256) void transpose_wo_kernel(
    const float* __restrict__ W, bf16* __restrict__ WT) {
    __shared__ float tile[64][65];
    const int c0 = blockIdx.x * 64, d0 = blockIdx.y * 64;
    for (int it = 0; it < 16; it++) {
        int e = it * 256 + threadIdx.x;
        int r = e >> 6, col = e & 63;
        tile[r][col] = W[(size_t)(c0 + r) * CDIM + d0 + col];
    }
    __syncthreads();
    for (int it = 0; it < 16; it++) {
        int e = it * 256 + threadIdx.x;
        int r = e >> 6, col = e & 63;
        WT[(size_t)(d0 + r) * CDIM + c0 + col] = __float2bfloat16(tile[col][r]);
    }
}

// V [bh][t][d] -> Vt [bh][d][t], 64x64 bf16 tiles
__global__ __launch_bounds__(256) void transpose_v_kernel(
    const bf16* __restrict__ V, bf16* __restrict__ Vt) {
    __shared__ unsigned short tile[64][65];
    const int bh = blockIdx.y, t0 = blockIdx.x * 64;
    const unsigned short* Vp  = (const unsigned short*)V + ((size_t)bh * TDIM + t0) * DH;
    unsigned short*       Vtp = (unsigned short*)Vt + (size_t)bh * DH * TDIM;
    for (int it = 0; it < 16; it++) {
        int e = it * 256 + threadIdx.x;
        int r = e >> 6, c = e & 63;
        tile[r][c] = Vp[(size_t)r * DH + c];
    }
    __syncthreads();
    for (int it = 0; it < 16; it++) {
        int e = it * 256 + threadIdx.x;
        int r = e >> 6, c = e & 63;
        Vtp[(size_t)r * TDIM + t0 + c] = tile[c][r];
    }
}

// ---------------------------------------------------------------------------
// 128x128 MFMA GEMM with global_load_lds staging (m97 pattern).
// QKV variant: z selects weight/bias/output; Q pre-scaled by 1/32.
// ---------------------------------------------------------------------------
__global__ __launch_bounds__(256) void proj_qkv_kernel(
    const bf16* __restrict__ X,
    const bf16* __restrict__ WqT, const bf16* __restrict__ WkT, const bf16* __restrict__ WvT,
    const bf16* __restrict__ bq,  const bf16* __restrict__ bk,  const bf16* __restrict__ bvv,
    bf16* __restrict__ Qo, bf16* __restrict__ Ko, bf16* __restrict__ Vo)
{
    const int z = blockIdx.z;
    const bf16* Bt   = (z == 0) ? WqT : (z == 1) ? WkT : WvT;
    const bf16* bias = (z == 0) ? bq  : (z == 1) ? bk  : bvv;

    __shared__ __align__(16) bf16 As[128 * 32];
    __shared__ __align__(16) bf16 Bs[128 * 32];

    const int tid  = threadIdx.x;
    const int lane = tid & 63;
    const int wave = tid >> 6;
    const int wr = wave >> 1, wc = wave & 1;
    const int l15 = lane & 15, quad = lane >> 4;

    const int blockM = blockIdx.y * 128;
    const int blockN = blockIdx.x * 128;

    f32x4 acc[4][4];
    for (int i = 0; i < 4; i++)
        for (int j = 0; j < 4; j++)
            acc[i][j] = (f32x4){0.f, 0.f, 0.f, 0.f};

    const int srow = lane >> 2, scol = (lane & 3) * 8;
    for (int k0 = 0; k0 < CDIM; k0 += 32) {
        for (int cc = 0; cc < 2; cc++) {
            int chunk = wave * 2 + cc;
            int row = chunk * 16 + srow;
            async_ld16(&X [(size_t)(blockM + row) * CDIM + k0 + scol], &As[chunk * 512]);
            async_ld16(&Bt[(size_t)(blockN + row) * CDIM + k0 + scol], &Bs[chunk * 512]);
        }
        __syncthreads();

        bf16x8 af[4], bfr[4];
        for (int mi = 0; mi < 4; mi++)
            af[mi] = *(const bf16x8*)&As[(wr * 64 + mi * 16 + l15) * 32 + quad * 8];
        for (int ni = 0; ni < 4; ni++)
            bfr[ni] = *(const bf16x8*)&Bs[(wc * 64 + ni * 16 + l15) * 32 + quad * 8];

        for (int mi = 0; mi < 4; mi++)
            for (int ni = 0; ni < 4; ni++)
                acc[mi][ni] = __builtin_amdgcn_mfma_f32_16x16x32_bf16(
                    af[mi], bfr[ni], acc[mi][ni], 0, 0, 0);
        __syncthreads();
    }

    for (int mi = 0; mi < 4; mi++) {
        int mbase = blockM + wr * 64 + mi * 16 + quad * 4;
        for (int ni = 0; ni < 4; ni++) {
            int n = blockN + wc * 64 + ni * 16 + l15;
            float bval = __bfloat162float(bias[n]);
            int h = n >> 6, d = n & 63;
            for (int r = 0; r < 4; r++) {
                int mm = mbase + r;
                int b = mm >> 11, t = mm & 2047;
                float val = acc[mi][ni][r] + bval;
                size_t idx = (((size_t)b * HDIM + h) * TDIM + t) * DH + d;
                if (z == 0)      Qo[idx] = __float2bfloat16(val * 0.03125f);
                else if (z == 1) Ko[idx] = __float2bfloat16(val);
                else             Vo[idx] = __float2bfloat16(val);
            }
        }
    }
}

// ---------------------------------------------------------------------------
// Output projection: Y[M,K] @ WoT[N,K]^T + bo -> fp32 Out
// ---------------------------------------------------------------------------
__global__ __launch_bounds__(256) void proj_out_kernel(
    const bf16* __restrict__ X, const bf16* __restrict__ Bt,
    const bf16* __restrict__ bias, float* __restrict__ Out)
{
    __shared__ __align__(16) bf16 As[128 * 32];
    __shared__ __align__(16) bf16 Bs[128 * 32];

    const int tid  = threadIdx.x;
    const int lane = tid & 63;
    const int wave = tid >> 6;
    const int wr = wave >> 1, wc = wave & 1;
    const int l15 = lane & 15, quad = lane >> 4;

    const int blockM = blockIdx.y * 128;
    const int blockN = blockIdx.x * 128;

    f32x4 acc[4][4];
    for (int i = 0; i < 4; i++)
        for (int j = 0; j < 4; j++)
            acc[i][j] = (f32x4){0.f, 0.f, 0.f, 0.f};

    const int srow = lane >> 2, scol = (lane & 3) * 8;
    for (int k0 = 0; k0 < CDIM; k0 += 32) {
        for (int cc = 0; cc < 2; cc++) {
            int chunk = wave * 2 + cc;
            int row = chunk * 16 + srow;
            async_ld16(&X [(size_t)(blockM + row) * CDIM + k0 + scol], &As[chunk * 512]);
            async_ld16(&Bt[(size_t)(blockN + row) * CDIM + k0 + scol], &Bs[chunk * 512]);
        }
        __syncthreads();

        bf16x8 af[4], bfr[4];
        for (int mi = 0; mi < 4; mi++)
            af[mi] = *(const bf16x8*)&As[(wr * 64 + mi * 16 + l15) * 32 + quad * 8];
        for (int ni = 0; ni < 4; ni++)
            bfr[ni] = *(const bf16x8*)&Bs[(wc * 64 + ni * 16 + l15) * 32 + quad * 8];

        for (int mi = 0; mi < 4; mi++)
            for (int ni = 0; ni < 4; ni++)
                acc[mi][ni] = __builtin_amdgcn_mfma_f32_16x16x32_bf16(
                    af[mi], bfr[ni], acc[mi][ni], 0, 0, 0);
        __syncthreads();
    }

    for (int mi = 0; mi < 4; mi++) {
        int mbase = blockM + wr * 64 + mi * 16 + quad * 4;
        for (int ni = 0; ni < 4; ni++) {
            int n = blockN + wc * 64 + ni * 16 + l15;
            float bval = __bfloat162float(bias[n]);
            for (int r = 0; r < 4; r++)
                Out[(size_t)(mbase + r) * CDIM + n] = acc[mi][ni][r] + bval;
        }
    }
}

// ---------------------------------------------------------------------------
// Flash attention, causal.  64-q tiles, 4 waves (256 thr), P-in-registers.
// Round-0 structure with the g-group loop removed and grid.x doubled to 32:
// 2048 blocks = 8 blocks/CU (LDS 18.4KB) x 4 waves = 32 waves/CU ceiling.
// __launch_bounds__(256, 4): rounds 1 & 3 proved that forcing 8 waves/EU
// (64-VGPR cap) makes the allocator spill the loop state (o[4]+qf+prefetch
// ~55-60 live) -> 0.5-1 GB of scratch traffic, 4x slower.  With the cap at
// 128 the compiler lands ~48-56 VGPR (round 0: 56 with MORE state), which is
// <=64, so hardware STILL fits 8 waves/SIMD -> full occupancy without spills.
// Each wave owns q rows qBase + wave*16 + l15.  S^T = K.Q^T exits QK in
// [key=quad*4+r][q=l15] layout == B-operand of 16x16x16 MFMA -> exp in regs
// feeds PV directly, NO LDS round-trip for P.  Diag masking on kt==qT only.
// ---------------------------------------------------------------------------
__global__ __launch_bounds__(256, 4) void attn_kernel(
    const bf16* __restrict__ Q, const bf16* __restrict__ Kb,
    const bf16* __restrict__ Vt, bf16* __restrict__ Y)
{
    const int bh    = blockIdx.y;
    const int qT    = (int)gridDim.x - 1 - blockIdx.x;   // 0..31, heavy first
    const int qBase = qT * 64;
    const int tid  = threadIdx.x;
    const int lane = tid & 63, wave = tid >> 6;          // wave 0..3
    const int l15 = lane & 15, quad = lane >> 4;

    __shared__ __align__(16) bf16 Ks[64 * 72];       // [key][dh]
    __shared__ __align__(16) bf16 Vs[64 * 72];       // [dh][key]

    // Q B-fragments: this wave's 16 q rows
    const size_t qrow = (size_t)bh * TDIM + qBase + wave * 16 + l15;
    const bf16x8 qf0 = *(const bf16x8*)&Q[qrow * DH + quad * 8];
    const bf16x8 qf1 = *(const bf16x8*)&Q[qrow * DH + 32 + quad * 8];

    // O^T accumulators: o[mt][r] -> d = mt*16+quad*4+r, q = l15
    f32x4 o[4];
    for (int mt = 0; mt < 4; mt++) o[mt] = (f32x4){0.f, 0.f, 0.f, 0.f};
    float lsum = 0.f;

    // staging coords: 256 threads x 2 chunks x 8 bf16 = 64x64 tile per array
    const int r0 = tid >> 3, kc0 = (tid & 7) * 8;

    const int nkt  = qT + 1;
    const int qloc = wave * 16 + l15;    // q offset within this 64-q tile

    uint4 kreg0 = *(const uint4*)&Kb[((size_t)bh * TDIM + r0) * DH + kc0];
    uint4 kreg1 = *(const uint4*)&Kb[((size_t)bh * TDIM + r0 + 32) * DH + kc0];
    uint4 vreg0 = *(const uint4*)&Vt[((size_t)bh * DH + r0) * TDIM + kc0];
    uint4 vreg1 = *(const uint4*)&Vt[((size_t)bh * DH + r0 + 32) * TDIM + kc0];

    for (int kt = 0; kt < nkt; kt++) {
        *(uint4*)&Ks[r0 * 72 + kc0]        = kreg0;
        *(uint4*)&Ks[(r0 + 32) * 72 + kc0] = kreg1;
        *(uint4*)&Vs[r0 * 72 + kc0]        = vreg0;
        *(uint4*)&Vs[(r0 + 32) * 72 + kc0] = vreg1;
        __syncthreads();

        if (kt + 1 < nkt) {
            const int nb = (kt + 1) * 64;
            kreg0 = *(const uint4*)&Kb[((size_t)bh * TDIM + nb + r0) * DH + kc0];
            kreg1 = *(const uint4*)&Kb[((size_t)bh * TDIM + nb + r0 + 32) * DH + kc0];
            vreg0 = *(const uint4*)&Vt[((size_t)bh * DH + r0) * TDIM + nb + kc0];
            vreg1 = *(const uint4*)&Vt[((size_t)bh * DH + r0 + 32) * TDIM + nb + kc0];
        }

        const bool diag = (kt == qT);
        for (int nt = 0; nt < 4; nt++) {
            // K A-frag for this 16-key chunk
            bf16x8 kf0 = *(const bf16x8*)&Ks[(nt * 16 + l15) * 72 + quad * 8];
            bf16x8 kf1 = *(const bf16x8*)&Ks[(nt * 16 + l15) * 72 + 32 + quad * 8];
            // V A-frags (16x16x16): A[m=d mt*16+l15][k=key nt*16+quad*4+j]
            bf16x4 vA[4];
            for (int mt = 0; mt < 4; mt++)
                vA[mt] = *(const bf16x4*)&Vs[(mt * 16 + l15) * 72 + nt * 16 + quad * 4];

            f32x4 s = (f32x4){0.f, 0.f, 0.f, 0.f};
            s = __builtin_amdgcn_mfma_f32_16x16x32_bf16(kf0, qf0, s, 0, 0, 0);
            s = __builtin_amdgcn_mfma_f32_16x16x32_bf16(kf1, qf1, s, 0, 0, 0);

            bf16x4 pb;
            for (int r = 0; r < 4; r++) {
                float pe = __expf(s[r]);
                if (diag && (nt * 16 + quad * 4 + r > qloc)) pe = 0.f;
                lsum += pe;
                pb[r] = (short)bf16bits(pe);
            }
            for (int mt = 0; mt < 4; mt++)
                o[mt] = mfma_16x16x16_bf16(vA[mt], pb, o[mt]);
        }
        __syncthreads();
    }

    // ---- epilogue: normalize, per-wave LDS transpose, coalesced store ----
    float v = lsum;
    v += __shfl_xor(v, 16, 64);
    v += __shfl_xor(v, 32, 64);
    const float inv = 1.0f / v;

    // o -> LDS wave-private slice [q=l15 row][d col]  (reuse Ks)
    unsigned short* sm = (unsigned short*)Ks;
    for (int mt = 0; mt < 4; mt++) {
        unsigned short pk[4];
        for (int r = 0; r < 4; r++) pk[r] = bf16bits(o[mt][r] * inv);
        *(ushort4*)&sm[(wave * 16 + l15) * 72 + mt * 16 + quad * 4] = *(ushort4*)pk;
    }
    // same-wave readback, coalesced global store
    const int b = bh >> 4, h = bh & 15;
    const int qq = lane >> 2, part = lane & 3;
    const int t = qBase + wave * 16 + qq;
    uint4 c0 = *(const uint4*)&sm[(wave * 16 + qq) * 72 + part * 16];
    uint4 c1 = *(const uint4*)&sm[(wave * 16 + qq) * 72 + part * 16 + 8];
    *(uint4*)&Y[((size_t)b * TDIM + t) * CDIM + h * DH + part * 16]     = c0;
    *(uint4*)&Y[((size_t)b * TDIM + t) * CDIM + h * DH + part * 16 + 8] = c1;
}

// ---------------------------------------------------------------------------
extern "C" void kernel_launch(void* const* d_in, const int* in_sizes, int n_in,
                              void* d_out, int out_size, void* d_ws, size_t ws_size,
                              hipStream_t stream) {
    (void)in_sizes; (void)n_in; (void)out_size; (void)ws_size;

    char* ws = (char*)d_ws;
    const size_t SZ_BHTD = (size_t)BDIM * HDIM * TDIM * DH * sizeof(bf16);  // 16 MiB
    const size_t SZ_W    = (size_t)HDIM * CDIM * DH * sizeof(bf16);         // 2 MiB
    bf16* Qb  = (bf16*)(ws);
    bf16* Kb  = (bf16*)(ws + SZ_BHTD);
    bf16* Vt  = (bf16*)(ws + 2 * SZ_BHTD);
    bf16* Y   = (bf16*)(ws + 3 * SZ_BHTD);
    bf16* WqT = (bf16*)(ws + 4 * SZ_BHTD);
    bf16* WkT = (bf16*)(ws + 4 * SZ_BHTD + SZ_W);
    bf16* WvT = (bf16*)(ws + 4 * SZ_BHTD + 2 * SZ_W);
    bf16* WoT = (bf16*)(ws + 4 * SZ_BHTD + 3 * SZ_W);
    bf16* xC  = (bf16*)(ws + 4 * SZ_BHTD + 4 * SZ_W);                       // 16 MiB
    bf16* bqC = (bf16*)(ws + 5 * SZ_BHTD + 4 * SZ_W);
    bf16* bkC = bqC + 1024;
    bf16* bvC = bqC + 2048;
    bf16* boC = bqC + 3072;
    bf16* Vb  = (bf16*)d_out;   // scratch: V [bh][t][d] lives in d_out until proj_out

    const int nX4 = (BDIM * TDIM * CDIM) / 4;
    convert_x4<<<nX4 / 256, 256, 0, stream>>>((const float4*)d_in[0], (ushort4*)xC, nX4);
    convert_biases<<<16, 256, 0, stream>>>((const float*)d_in[2], (const float*)d_in[4],
                                           (const float*)d_in[6], (const float*)d_in[8], bqC);

    transpose_qkv_kernel<<<dim3(CDIM / 64, 1, 48), 256, 0, stream>>>(
        (const float*)d_in[1], (const float*)d_in[3], (const float*)d_in[5], WqT, WkT, WvT);
    transpose_wo_kernel<<<dim3(CDIM / 64, CDIM / 64), 256, 0, stream>>>(
        (const float*)d_in[7], WoT);

    dim3 gq(CDIM / 128, (BDIM * TDIM) / 128, 3);
    proj_qkv_kernel<<<gq, 256, 0, stream>>>(xC, WqT, WkT, WvT, bqC, bkC, bvC, Qb, Kb, Vb);

    transpose_v_kernel<<<dim3(TDIM / 64, BDIM * HDIM), 256, 0, stream>>>(Vb, Vt);

    attn_kernel<<<dim3(TDIM / 64, BDIM * HDIM), 256, 0, stream>>>(Qb, Kb, Vt, Y);

    proj_out_kernel<<<dim3(CDIM / 128, (BDIM * TDIM) / 128), 256, 0, stream>>>(
        Y, WoT, boC, (float*)d_out);
}

// Round 5
// 306.404 us; speedup vs baseline: 1.9465x; 1.0698x over previous
//
#include <hip/hip_runtime.h>
#include <hip/hip_bf16.h>

#define TDIM 2048
#define BDIM 4
#define CDIM 1024
#define HDIM 16
#define DH   64

typedef __hip_bfloat16 bf16;
typedef __attribute__((ext_vector_type(8))) short bf16x8;
typedef __attribute__((ext_vector_type(4))) short bf16x4;
typedef __attribute__((ext_vector_type(4))) float f32x4;

// async global->LDS, 16B per lane; LDS dest = wave-uniform base + lane*16
__device__ __forceinline__ void async_ld16(const bf16* g, bf16* l) {
    __builtin_amdgcn_global_load_lds(
        (const __attribute__((address_space(1))) unsigned int*)g,
        (__attribute__((address_space(3))) unsigned int*)l, 16, 0, 0);
}

__device__ __forceinline__ unsigned short bf16bits(float x) {
    bf16 b = __float2bfloat16(x);
    return *(unsigned short*)&b;
}

// 16x16x16 bf16 MFMA (k=16): verified working (passed correctness)
__device__ __forceinline__ f32x4 mfma_16x16x16_bf16(bf16x4 a, bf16x4 b, f32x4 c) {
#if __has_builtin(__builtin_amdgcn_mfma_f32_16x16x16_bf16)
    return __builtin_amdgcn_mfma_f32_16x16x16_bf16(a, b, c, 0, 0, 0);
#elif __has_builtin(__builtin_amdgcn_mfma_f32_16x16x16bf16_1k)
    return __builtin_amdgcn_mfma_f32_16x16x16bf16_1k(a, b, c, 0, 0, 0);
#else
    asm volatile("v_mfma_f32_16x16x16_bf16 %0, %1, %2, %0"
                 : "+v"(c) : "v"(a), "v"(b));
    return c;
#endif
}

// ---------------------------------------------------------------------------
__global__ void convert_x4(const float4* __restrict__ src, ushort4* __restrict__ dst, int n4) {
    int i = blockIdx.x * blockDim.x + threadIdx.x;
    if (i >= n4) return;
    float4 v = src[i];
    ushort4 o;
    o.x = bf16bits(v.x); o.y = bf16bits(v.y);
    o.z = bf16bits(v.z); o.w = bf16bits(v.w);
    dst[i] = o;
}

__global__ void convert_biases(const float* __restrict__ b0, const float* __restrict__ b1,
                               const float* __restrict__ b2, const float* __restrict__ b3,
                               bf16* __restrict__ dst) {
    int i = blockIdx.x * blockDim.x + threadIdx.x;   // 0..4095
    int which = i >> 10, j = i & 1023;
    const float* src = (which == 0) ? b0 : (which == 1) ? b1 : (which == 2) ? b2 : b3;
    dst[i] = __float2bfloat16(src[j]);
}

// ---------------------------------------------------------------------------
// LDS-tiled transpose, fused over Wq/Wk/Wv: z = which*16 + h.
// ---------------------------------------------------------------------------
__global__ __launch_bounds__(256) void transpose_qkv_kernel(
    const float* __restrict__ Wq, const float* __restrict__ Wk, const float* __restrict__ Wv,
    bf16* __restrict__ WqT, bf16* __restrict__ WkT, bf16* __restrict__ WvT) {
    __shared__ float tile[64][65];
    const int which = blockIdx.z >> 4, h = blockIdx.z & 15;
    const float* W  = ((which == 0) ? Wq  : (which == 1) ? Wk  : Wv)  + (size_t)h * CDIM * DH;
    bf16*        WT = ((which == 0) ? WqT : (which == 1) ? WkT : WvT) + (size_t)h * CDIM * DH;
    const int c0 = blockIdx.x * 64;
    for (int it = 0; it < 16; it++) {
        int e = it * 256 + threadIdx.x;
        int r = e >> 6, col = e & 63;
        tile[r][col] = W[(size_t)(c0 + r) * DH + col];
    }
    __syncthreads();
    for (int it = 0; it < 16; it++) {
        int e = it * 256 + threadIdx.x;
        int r = e >> 6, col = e & 63;
        WT[(size_t)r * CDIM + c0 + col] = __float2bfloat16(tile[col][r]);
    }
}

__global__ __launch_bounds__(256) void transpose_wo_kernel(
    const float* __restrict__ W, bf16* __restrict__ WT) {
    __shared__ float tile[64][65];
    const int c0 = blockIdx.x * 64, d0 = blockIdx.y * 64;
    for (int it = 0; it < 16; it++) {
        int e = it * 256 + threadIdx.x;
        int r = e >> 6, col = e & 63;
        tile[r][col] = W[(size_t)(c0 + r) * CDIM + d0 + col];
    }
    __syncthreads();
    for (int it = 0; it < 16; it++) {
        int e = it * 256 + threadIdx.x;
        int r = e >> 6, col = e & 63;
        WT[(size_t)(d0 + r) * CDIM + c0 + col] = __float2bfloat16(tile[col][r]);
    }
}

// V [bh][t][d] -> Vt [bh][d][t], 64x64 bf16 tiles
__global__ __launch_bounds__(256) void transpose_v_kernel(
    const bf16* __restrict__ V, bf16* __restrict__ Vt) {
    __shared__ unsigned short tile[64][65];
    const int bh = blockIdx.y, t0 = blockIdx.x * 64;
    const unsigned short* Vp  = (const unsigned short*)V + ((size_t)bh * TDIM + t0) * DH;
    unsigned short*       Vtp = (unsigned short*)Vt + (size_t)bh * DH * TDIM;
    for (int it = 0; it < 16; it++) {
        int e = it * 256 + threadIdx.x;
        int r = e >> 6, c = e & 63;
        tile[r][c] = Vp[(size_t)r * DH + c];
    }
    __syncthreads();
    for (int it = 0; it < 16; it++) {
        int e = it * 256 + threadIdx.x;
        int r = e >> 6, c = e & 63;
        Vtp[(size_t)r * TDIM + t0 + c] = tile[c][r];
    }
}

// ---------------------------------------------------------------------------
// 128x128 MFMA GEMM with global_load_lds staging (m97 pattern).
// QKV variant: z selects weight/bias/output; Q pre-scaled by 1/32.
// ---------------------------------------------------------------------------
__global__ __launch_bounds__(256) void proj_qkv_kernel(
    const bf16* __restrict__ X,
    const bf16* __restrict__ WqT, const bf16* __restrict__ WkT, const bf16* __restrict__ WvT,
    const bf16* __restrict__ bq,  const bf16* __restrict__ bk,  const bf16* __restrict__ bvv,
    bf16* __restrict__ Qo, bf16* __restrict__ Ko, bf16* __restrict__ Vo)
{
    const int z = blockIdx.z;
    const bf16* Bt   = (z == 0) ? WqT : (z == 1) ? WkT : WvT;
    const bf16* bias = (z == 0) ? bq  : (z == 1) ? bk  : bvv;

    __shared__ __align__(16) bf16 As[128 * 32];
    __shared__ __align__(16) bf16 Bs[128 * 32];

    const int tid  = threadIdx.x;
    const int lane = tid & 63;
    const int wave = tid >> 6;
    const int wr = wave >> 1, wc = wave & 1;
    const int l15 = lane & 15, quad = lane >> 4;

    const int blockM = blockIdx.y * 128;
    const int blockN = blockIdx.x * 128;

    f32x4 acc[4][4];
    for (int i = 0; i < 4; i++)
        for (int j = 0; j < 4; j++)
            acc[i][j] = (f32x4){0.f, 0.f, 0.f, 0.f};

    const int srow = lane >> 2, scol = (lane & 3) * 8;
    for (int k0 = 0; k0 < CDIM; k0 += 32) {
        for (int cc = 0; cc < 2; cc++) {
            int chunk = wave * 2 + cc;
            int row = chunk * 16 + srow;
            async_ld16(&X [(size_t)(blockM + row) * CDIM + k0 + scol], &As[chunk * 512]);
            async_ld16(&Bt[(size_t)(blockN + row) * CDIM + k0 + scol], &Bs[chunk * 512]);
        }
        __syncthreads();

        bf16x8 af[4], bfr[4];
        for (int mi = 0; mi < 4; mi++)
            af[mi] = *(const bf16x8*)&As[(wr * 64 + mi * 16 + l15) * 32 + quad * 8];
        for (int ni = 0; ni < 4; ni++)
            bfr[ni] = *(const bf16x8*)&Bs[(wc * 64 + ni * 16 + l15) * 32 + quad * 8];

        for (int mi = 0; mi < 4; mi++)
            for (int ni = 0; ni < 4; ni++)
                acc[mi][ni] = __builtin_amdgcn_mfma_f32_16x16x32_bf16(
                    af[mi], bfr[ni], acc[mi][ni], 0, 0, 0);
        __syncthreads();
    }

    for (int mi = 0; mi < 4; mi++) {
        int mbase = blockM + wr * 64 + mi * 16 + quad * 4;
        for (int ni = 0; ni < 4; ni++) {
            int n = blockN + wc * 64 + ni * 16 + l15;
            float bval = __bfloat162float(bias[n]);
            int h = n >> 6, d = n & 63;
            for (int r = 0; r < 4; r++) {
                int mm = mbase + r;
                int b = mm >> 11, t = mm & 2047;
                float val = acc[mi][ni][r] + bval;
                size_t idx = (((size_t)b * HDIM + h) * TDIM + t) * DH + d;
                if (z == 0)      Qo[idx] = __float2bfloat16(val * 0.03125f);
                else if (z == 1) Ko[idx] = __float2bfloat16(val);
                else             Vo[idx] = __float2bfloat16(val);
            }
        }
    }
}

// ---------------------------------------------------------------------------
// Output projection: Y[M,K] @ WoT[N,K]^T + bo -> fp32 Out
// ---------------------------------------------------------------------------
__global__ __launch_bounds__(256) void proj_out_kernel(
    const bf16* __restrict__ X, const bf16* __restrict__ Bt,
    const bf16* __restrict__ bias, float* __restrict__ Out)
{
    __shared__ __align__(16) bf16 As[128 * 32];
    __shared__ __align__(16) bf16 Bs[128 * 32];

    const int tid  = threadIdx.x;
    const int lane = tid & 63;
    const int wave = tid >> 6;
    const int wr = wave >> 1, wc = wave & 1;
    const int l15 = lane & 15, quad = lane >> 4;

    const int blockM = blockIdx.y * 128;
    const int blockN = blockIdx.x * 128;

    f32x4 acc[4][4];
    for (int i = 0; i < 4; i++)
        for (int j = 0; j < 4; j++)
            acc[i][j] = (f32x4){0.f, 0.f, 0.f, 0.f};

    const int srow = lane >> 2, scol = (lane & 3) * 8;
    for (int k0 = 0; k0 < CDIM; k0 += 32) {
        for (int cc = 0; cc < 2; cc++) {
            int chunk = wave * 2 + cc;
            int row = chunk * 16 + srow;
            async_ld16(&X [(size_t)(blockM + row) * CDIM + k0 + scol], &As[chunk * 512]);
            async_ld16(&Bt[(size_t)(blockN + row) * CDIM + k0 + scol], &Bs[chunk * 512]);
        }
        __syncthreads();

        bf16x8 af[4], bfr[4];
        for (int mi = 0; mi < 4; mi++)
            af[mi] = *(const bf16x8*)&As[(wr * 64 + mi * 16 + l15) * 32 + quad * 8];
        for (int ni = 0; ni < 4; ni++)
            bfr[ni] = *(const bf16x8*)&Bs[(wc * 64 + ni * 16 + l15) * 32 + quad * 8];

        for (int mi = 0; mi < 4; mi++)
            for (int ni = 0; ni < 4; ni++)
                acc[mi][ni] = __builtin_amdgcn_mfma_f32_16x16x32_bf16(
                    af[mi], bfr[ni], acc[mi][ni], 0, 0, 0);
        __syncthreads();
    }

    for (int mi = 0; mi < 4; mi++) {
        int mbase = blockM + wr * 64 + mi * 16 + quad * 4;
        for (int ni = 0; ni < 4; ni++) {
            int n = blockN + wc * 64 + ni * 16 + l15;
            float bval = __bfloat162float(bias[n]);
            for (int r = 0; r < 4; r++)
                Out[(size_t)(mbase + r) * CDIM + n] = acc[mi][ni][r] + bval;
        }
    }
}

// ---------------------------------------------------------------------------
// Flash attention, causal.  64-q tiles, 4 waves, P-in-registers, and
// global_load_lds K/V staging with XOR-swizzled LDS (both-sides pattern).
//
// Round-4 post-mortem: the 16 VGPRs of register prefetch (kreg/vreg) held
// live across the compute section pushed VGPR_Count to exactly 64, which
// empirically halves waves/SIMD (round 3 @32 VGPR -> 44% occ; round 4 @64
// -> 18.5%).  This version stages K/V via global_load_lds (no VGPR round
// trip) into LINEAR stride-64 LDS rows (128B).  Linear rows alone = 16-way
// bank conflict on fragment reads, so col16 units are XOR-swizzled by
// (row&7): the global SOURCE address per lane is inverse-permuted (since
// each wave-call covers exactly 8 rows, this is the per-lane constant
// (lane&7)^(lane>>3)), and every LDS READ applies the same XOR.  LDS drops
// 18.4->16KB.  Predicted VGPR ~48 -> 8 waves/SIMD, occupancy 2x.
// ---------------------------------------------------------------------------
__global__ __launch_bounds__(256, 4) void attn_kernel(
    const bf16* __restrict__ Q, const bf16* __restrict__ Kb,
    const bf16* __restrict__ Vt, bf16* __restrict__ Y)
{
    const int bh    = blockIdx.y;
    const int qT    = (int)gridDim.x - 1 - blockIdx.x;   // 0..31, heavy first
    const int qBase = qT * 64;
    const int tid  = threadIdx.x;
    const int lane = tid & 63, wave = tid >> 6;          // wave 0..3
    const int l15 = lane & 15, quad = lane >> 4;

    __shared__ __align__(16) bf16 smem[2 * 64 * 64];     // 16 KiB
    bf16* Ks = smem;             // [key][dh swz], stride 64
    bf16* Vs = smem + 64 * 64;   // [dh][key swz], stride 64

    // Q B-fragments: this wave's 16 q rows
    const size_t qrow = (size_t)bh * TDIM + qBase + wave * 16 + l15;
    const bf16x8 qf0 = *(const bf16x8*)&Q[qrow * DH + quad * 8];
    const bf16x8 qf1 = *(const bf16x8*)&Q[qrow * DH + 32 + quad * 8];

    // O^T accumulators: o[mt][r] -> d = mt*16+quad*4+r, q = l15
    f32x4 o[4];
    for (int mt = 0; mt < 4; mt++) o[mt] = (f32x4){0.f, 0.f, 0.f, 0.f};
    float lsum = 0.f;

    // --- staging geometry: wave w, chunk cc covers rows w*16+cc*8..+7 ------
    // lane l: row = base + (l>>3); since base%8==0, row&7 == l>>3.
    // inverse-swizzled source col16 = (l&7) ^ (l>>3)  (per-lane constant)
    const int srow = (wave << 4) + (lane >> 3);                 // cc=0 row
    const int ssc  = (((lane & 7) ^ (lane >> 3)) << 3);         // elem offset
    // K source: row = key within tile; V source: row = d
    const bf16* kSrc0 = Kb + ((size_t)bh * TDIM + srow) * DH + ssc;         // + kt*64*DH, +cc*8*DH
    const bf16* vSrc0 = Vt + ((size_t)bh * DH + srow) * TDIM + ssc;         // + kt*64,    +cc*8*TDIM

    // read-side swizzle constants
    const int swA   = l15 & 7;                         // row&7 for fragment rows
    const int kcol0 = ((quad ^ swA) << 3);             // logical col16=quad
    const int kcol1 = (((4 + quad) ^ swA) << 3);       // logical col16=4+quad
    const int u2    = quad >> 1, intra = ((quad & 1) << 2);

    const int nkt  = qT + 1;
    const int qloc = wave * 16 + l15;    // q offset within this 64-q tile

    for (int kt = 0; kt < nkt; kt++) {
        // ---- async stage K and V tiles (linear LDS, pre-swizzled source) --
        {
            const bf16* kS = kSrc0 + (size_t)kt * 64 * DH;
            const bf16* vS = vSrc0 + (size_t)kt * 64;
            bf16* kD = Ks + (wave * 16) * 64;
            bf16* vD = Vs + (wave * 16) * 64;
            async_ld16(kS,            kD);
            async_ld16(kS + 8 * DH,   kD + 8 * 64);
            async_ld16(vS,            vD);
            async_ld16(vS + 8 * TDIM, vD + 8 * 64);
        }
        __syncthreads();   // drains vmcnt before any wave reads LDS

        const bool diag = (kt == qT);
        for (int nt = 0; nt < 4; nt++) {
            // K A-frag for this 16-key chunk (swizzled cols)
            bf16x8 kf0 = *(const bf16x8*)&Ks[(nt * 16 + l15) * 64 + kcol0];
            bf16x8 kf1 = *(const bf16x8*)&Ks[(nt * 16 + l15) * 64 + kcol1];
            // V A-frags (16x16x16): logical elem col nt*16+quad*4
            //   -> col16 u = nt*2+(quad>>1), intra-elem (quad&1)*4, XOR row&7
            bf16x4 vA[4];
            for (int mt = 0; mt < 4; mt++)
                vA[mt] = *(const bf16x4*)&Vs[(mt * 16 + l15) * 64 +
                                             (((nt * 2 + u2) ^ swA) << 3) + intra];

            f32x4 s = (f32x4){0.f, 0.f, 0.f, 0.f};
            s = __builtin_amdgcn_mfma_f32_16x16x32_bf16(kf0, qf0, s, 0, 0, 0);
            s = __builtin_amdgcn_mfma_f32_16x16x32_bf16(kf1, qf1, s, 0, 0, 0);

            bf16x4 pb;
            for (int r = 0; r < 4; r++) {
                float pe = __expf(s[r]);
                if (diag && (nt * 16 + quad * 4 + r > qloc)) pe = 0.f;
                lsum += pe;
                pb[r] = (short)bf16bits(pe);
            }
            for (int mt = 0; mt < 4; mt++)
                o[mt] = mfma_16x16x16_bf16(vA[mt], pb, o[mt]);
        }
        __syncthreads();
    }

    // ---- epilogue: normalize, per-wave LDS transpose, coalesced store ----
    float v = lsum;
    v += __shfl_xor(v, 16, 64);
    v += __shfl_xor(v, 32, 64);
    const float inv = 1.0f / v;

    // o -> LDS wave-private slice [q row][d col], stride 72 over smem scratch
    // (max index 63*72+64 = 4600 elems < 8192 available)
    unsigned short* sm = (unsigned short*)smem;
    for (int mt = 0; mt < 4; mt++) {
        unsigned short pk[4];
        for (int r = 0; r < 4; r++) pk[r] = bf16bits(o[mt][r] * inv);
        *(ushort4*)&sm[(wave * 16 + l15) * 72 + mt * 16 + quad * 4] = *(ushort4*)pk;
    }
    // same-wave readback, coalesced global store
    const int b = bh >> 4, h = bh & 15;
    const int qq = lane >> 2, part = lane & 3;
    const int t = qBase + wave * 16 + qq;
    uint4 c0 = *(const uint4*)&sm[(wave * 16 + qq) * 72 + part * 16];
    uint4 c1 = *(const uint4*)&sm[(wave * 16 + qq) * 72 + part * 16 + 8];
    *(uint4*)&Y[((size_t)b * TDIM + t) * CDIM + h * DH + part * 16]     = c0;
    *(uint4*)&Y[((size_t)b * TDIM + t) * CDIM + h * DH + part * 16 + 8] = c1;
}

// ---------------------------------------------------------------------------
extern "C" void kernel_launch(void* const* d_in, const int* in_sizes, int n_in,
                              void* d_out, int out_size, void* d_ws, size_t ws_size,
                              hipStream_t stream) {
    (void)in_sizes; (void)n_in; (void)out_size; (void)ws_size;

    char* ws = (char*)d_ws;
    const size_t SZ_BHTD = (size_t)BDIM * HDIM * TDIM * DH * sizeof(bf16);  // 16 MiB
    const size_t SZ_W    = (size_t)HDIM * CDIM * DH * sizeof(bf16);         // 2 MiB
    bf16* Qb  = (bf16*)(ws);
    bf16* Kb  = (bf16*)(ws + SZ_BHTD);
    bf16* Vt  = (bf16*)(ws + 2 * SZ_BHTD);
    bf16* Y   = (bf16*)(ws + 3 * SZ_BHTD);
    bf16* WqT = (bf16*)(ws + 4 * SZ_BHTD);
    bf16* WkT = (bf16*)(ws + 4 * SZ_BHTD + SZ_W);
    bf16* WvT = (bf16*)(ws + 4 * SZ_BHTD + 2 * SZ_W);
    bf16* WoT = (bf16*)(ws + 4 * SZ_BHTD + 3 * SZ_W);
    bf16* xC  = (bf16*)(ws + 4 * SZ_BHTD + 4 * SZ_W);                       // 16 MiB
    bf16* bqC = (bf16*)(ws + 5 * SZ_BHTD + 4 * SZ_W);
    bf16* bkC = bqC + 1024;
    bf16* bvC = bqC + 2048;
    bf16* boC = bqC + 3072;
    bf16* Vb  = (bf16*)d_out;   // scratch: V [bh][t][d] lives in d_out until proj_out

    const int nX4 = (BDIM * TDIM * CDIM) / 4;
    convert_x4<<<nX4 / 256, 256, 0, stream>>>((const float4*)d_in[0], (ushort4*)xC, nX4);
    convert_biases<<<16, 256, 0, stream>>>((const float*)d_in[2], (const float*)d_in[4],
                                           (const float*)d_in[6], (const float*)d_in[8], bqC);

    transpose_qkv_kernel<<<dim3(CDIM / 64, 1, 48), 256, 0, stream>>>(
        (const float*)d_in[1], (const float*)d_in[3], (const float*)d_in[5], WqT, WkT, WvT);
    transpose_wo_kernel<<<dim3(CDIM / 64, CDIM / 64), 256, 0, stream>>>(
        (const float*)d_in[7], WoT);

    dim3 gq(CDIM / 128, (BDIM * TDIM) / 128, 3);
    proj_qkv_kernel<<<gq, 256, 0, stream>>>(xC, WqT, WkT, WvT, bqC, bkC, bvC, Qb, Kb, Vb);

    transpose_v_kernel<<<dim3(TDIM / 64, BDIM * HDIM), 256, 0, stream>>>(Vb, Vt);

    attn_kernel<<<dim3(TDIM / 64, BDIM * HDIM), 256, 0, stream>>>(Qb, Kb, Vt, Y);

    proj_out_kernel<<<dim3(CDIM / 128, (BDIM * TDIM) / 128), 256, 0, stream>>>(
        Y, WoT, boC, (float*)d_out);
}

// Round 6
// 303.968 us; speedup vs baseline: 1.9621x; 1.0080x over previous
//
#include <hip/hip_runtime.h>
#include <hip/hip_bf16.h>

#define TDIM 2048
#define BDIM 4
#define CDIM 1024
#define HDIM 16
#define DH   64

typedef __hip_bfloat16 bf16;
typedef __attribute__((ext_vector_type(8))) short bf16x8;
typedef __attribute__((ext_vector_type(4))) short bf16x4;
typedef __attribute__((ext_vector_type(4))) float f32x4;

// async global->LDS, 16B per lane; LDS dest = wave-uniform base + lane*16
__device__ __forceinline__ void async_ld16(const bf16* g, bf16* l) {
    __builtin_amdgcn_global_load_lds(
        (const __attribute__((address_space(1))) unsigned int*)g,
        (__attribute__((address_space(3))) unsigned int*)l, 16, 0, 0);
}

__device__ __forceinline__ unsigned short bf16bits(float x) {
    bf16 b = __float2bfloat16(x);
    return *(unsigned short*)&b;
}

// v_exp_f32 is natively 2^x; exp2f avoids __expf's extra 1/ln2 multiply
__device__ __forceinline__ float fast_exp2(float x) {
#if __has_builtin(__builtin_amdgcn_exp2f)
    return __builtin_amdgcn_exp2f(x);
#else
    return exp2f(x);
#endif
}

// 16x16x16 bf16 MFMA (k=16): verified working (passed correctness)
__device__ __forceinline__ f32x4 mfma_16x16x16_bf16(bf16x4 a, bf16x4 b, f32x4 c) {
#if __has_builtin(__builtin_amdgcn_mfma_f32_16x16x16_bf16)
    return __builtin_amdgcn_mfma_f32_16x16x16_bf16(a, b, c, 0, 0, 0);
#elif __has_builtin(__builtin_amdgcn_mfma_f32_16x16x16bf16_1k)
    return __builtin_amdgcn_mfma_f32_16x16x16bf16_1k(a, b, c, 0, 0, 0);
#else
    asm volatile("v_mfma_f32_16x16x16_bf16 %0, %1, %2, %0"
                 : "+v"(c) : "v"(a), "v"(b));
    return c;
#endif
}

// ---------------------------------------------------------------------------
__global__ void convert_x4(const float4* __restrict__ src, ushort4* __restrict__ dst, int n4) {
    int i = blockIdx.x * blockDim.x + threadIdx.x;
    if (i >= n4) return;
    float4 v = src[i];
    ushort4 o;
    o.x = bf16bits(v.x); o.y = bf16bits(v.y);
    o.z = bf16bits(v.z); o.w = bf16bits(v.w);
    dst[i] = o;
}

__global__ void convert_biases(const float* __restrict__ b0, const float* __restrict__ b1,
                               const float* __restrict__ b2, const float* __restrict__ b3,
                               bf16* __restrict__ dst) {
    int i = blockIdx.x * blockDim.x + threadIdx.x;   // 0..4095
    int which = i >> 10, j = i & 1023;
    const float* src = (which == 0) ? b0 : (which == 1) ? b1 : (which == 2) ? b2 : b3;
    dst[i] = __float2bfloat16(src[j]);
}

// ---------------------------------------------------------------------------
// LDS-tiled transpose, fused over Wq/Wk/Wv: z = which*16 + h.
// ---------------------------------------------------------------------------
__global__ __launch_bounds__(256) void transpose_qkv_kernel(
    const float* __restrict__ Wq, const float* __restrict__ Wk, const float* __restrict__ Wv,
    bf16* __restrict__ WqT, bf16* __restrict__ WkT, bf16* __restrict__ WvT) {
    __shared__ float tile[64][65];
    const int which = blockIdx.z >> 4, h = blockIdx.z & 15;
    const float* W  = ((which == 0) ? Wq  : (which == 1) ? Wk  : Wv)  + (size_t)h * CDIM * DH;
    bf16*        WT = ((which == 0) ? WqT : (which == 1) ? WkT : WvT) + (size_t)h * CDIM * DH;
    const int c0 = blockIdx.x * 64;
    for (int it = 0; it < 16; it++) {
        int e = it * 256 + threadIdx.x;
        int r = e >> 6, col = e & 63;
        tile[r][col] = W[(size_t)(c0 + r) * DH + col];
    }
    __syncthreads();
    for (int it = 0; it < 16; it++) {
        int e = it * 256 + threadIdx.x;
        int r = e >> 6, col = e & 63;
        WT[(size_t)r * CDIM + c0 + col] = __float2bfloat16(tile[col][r]);
    }
}

__global__ __launch_bounds__(256) void transpose_wo_kernel(
    const float* __restrict__ W, bf16* __restrict__ WT) {
    __shared__ float tile[64][65];
    const int c0 = blockIdx.x * 64, d0 = blockIdx.y * 64;
    for (int it = 0; it < 16; it++) {
        int e = it * 256 + threadIdx.x;
        int r = e >> 6, col = e & 63;
        tile[r][col] = W[(size_t)(c0 + r) * CDIM + d0 + col];
    }
    __syncthreads();
    for (int it = 0; it < 16; it++) {
        int e = it * 256 + threadIdx.x;
        int r = e >> 6, col = e & 63;
        WT[(size_t)(d0 + r) * CDIM + c0 + col] = __float2bfloat16(tile[col][r]);
    }
}

// V [bh][t][d] -> Vt [bh][d][t], 64x64 bf16 tiles
__global__ __launch_bounds__(256) void transpose_v_kernel(
    const bf16* __restrict__ V, bf16* __restrict__ Vt) {
    __shared__ unsigned short tile[64][65];
    const int bh = blockIdx.y, t0 = blockIdx.x * 64;
    const unsigned short* Vp  = (const unsigned short*)V + ((size_t)bh * TDIM + t0) * DH;
    unsigned short*       Vtp = (unsigned short*)Vt + (size_t)bh * DH * TDIM;
    for (int it = 0; it < 16; it++) {
        int e = it * 256 + threadIdx.x;
        int r = e >> 6, c = e & 63;
        tile[r][c] = Vp[(size_t)r * DH + c];
    }
    __syncthreads();
    for (int it = 0; it < 16; it++) {
        int e = it * 256 + threadIdx.x;
        int r = e >> 6, c = e & 63;
        Vtp[(size_t)r * TDIM + t0 + c] = tile[c][r];
    }
}

// ---------------------------------------------------------------------------
// 128x128 MFMA GEMM with global_load_lds staging (m97 pattern).
// QKV variant: z selects weight/bias/output.
// Q pre-scaled by (1/32)*log2(e) so attention can use native exp2.
// ---------------------------------------------------------------------------
__global__ __launch_bounds__(256) void proj_qkv_kernel(
    const bf16* __restrict__ X,
    const bf16* __restrict__ WqT, const bf16* __restrict__ WkT, const bf16* __restrict__ WvT,
    const bf16* __restrict__ bq,  const bf16* __restrict__ bk,  const bf16* __restrict__ bvv,
    bf16* __restrict__ Qo, bf16* __restrict__ Ko, bf16* __restrict__ Vo)
{
    const int z = blockIdx.z;
    const bf16* Bt   = (z == 0) ? WqT : (z == 1) ? WkT : WvT;
    const bf16* bias = (z == 0) ? bq  : (z == 1) ? bk  : bvv;

    __shared__ __align__(16) bf16 As[128 * 32];
    __shared__ __align__(16) bf16 Bs[128 * 32];

    const int tid  = threadIdx.x;
    const int lane = tid & 63;
    const int wave = tid >> 6;
    const int wr = wave >> 1, wc = wave & 1;
    const int l15 = lane & 15, quad = lane >> 4;

    const int blockM = blockIdx.y * 128;
    const int blockN = blockIdx.x * 128;

    f32x4 acc[4][4];
    for (int i = 0; i < 4; i++)
        for (int j = 0; j < 4; j++)
            acc[i][j] = (f32x4){0.f, 0.f, 0.f, 0.f};

    const int srow = lane >> 2, scol = (lane & 3) * 8;
    for (int k0 = 0; k0 < CDIM; k0 += 32) {
        for (int cc = 0; cc < 2; cc++) {
            int chunk = wave * 2 + cc;
            int row = chunk * 16 + srow;
            async_ld16(&X [(size_t)(blockM + row) * CDIM + k0 + scol], &As[chunk * 512]);
            async_ld16(&Bt[(size_t)(blockN + row) * CDIM + k0 + scol], &Bs[chunk * 512]);
        }
        __syncthreads();

        bf16x8 af[4], bfr[4];
        for (int mi = 0; mi < 4; mi++)
            af[mi] = *(const bf16x8*)&As[(wr * 64 + mi * 16 + l15) * 32 + quad * 8];
        for (int ni = 0; ni < 4; ni++)
            bfr[ni] = *(const bf16x8*)&Bs[(wc * 64 + ni * 16 + l15) * 32 + quad * 8];

        for (int mi = 0; mi < 4; mi++)
            for (int ni = 0; ni < 4; ni++)
                acc[mi][ni] = __builtin_amdgcn_mfma_f32_16x16x32_bf16(
                    af[mi], bfr[ni], acc[mi][ni], 0, 0, 0);
        __syncthreads();
    }

    for (int mi = 0; mi < 4; mi++) {
        int mbase = blockM + wr * 64 + mi * 16 + quad * 4;
        for (int ni = 0; ni < 4; ni++) {
            int n = blockN + wc * 64 + ni * 16 + l15;
            float bval = __bfloat162float(bias[n]);
            int h = n >> 6, d = n & 63;
            for (int r = 0; r < 4; r++) {
                int mm = mbase + r;
                int b = mm >> 11, t = mm & 2047;
                float val = acc[mi][ni][r] + bval;
                size_t idx = (((size_t)b * HDIM + h) * TDIM + t) * DH + d;
                if (z == 0)      Qo[idx] = __float2bfloat16(val * 0.045084439f); // (1/32)*log2(e)
                else if (z == 1) Ko[idx] = __float2bfloat16(val);
                else             Vo[idx] = __float2bfloat16(val);
            }
        }
    }
}

// ---------------------------------------------------------------------------
// Output projection: Y[M,K] @ WoT[N,K]^T + bo -> fp32 Out
// ---------------------------------------------------------------------------
__global__ __launch_bounds__(256) void proj_out_kernel(
    const bf16* __restrict__ X, const bf16* __restrict__ Bt,
    const bf16* __restrict__ bias, float* __restrict__ Out)
{
    __shared__ __align__(16) bf16 As[128 * 32];
    __shared__ __align__(16) bf16 Bs[128 * 32];

    const int tid  = threadIdx.x;
    const int lane = tid & 63;
    const int wave = tid >> 6;
    const int wr = wave >> 1, wc = wave & 1;
    const int l15 = lane & 15, quad = lane >> 4;

    const int blockM = blockIdx.y * 128;
    const int blockN = blockIdx.x * 128;

    f32x4 acc[4][4];
    for (int i = 0; i < 4; i++)
        for (int j = 0; j < 4; j++)
            acc[i][j] = (f32x4){0.f, 0.f, 0.f, 0.f};

    const int srow = lane >> 2, scol = (lane & 3) * 8;
    for (int k0 = 0; k0 < CDIM; k0 += 32) {
        for (int cc = 0; cc < 2; cc++) {
            int chunk = wave * 2 + cc;
            int row = chunk * 16 + srow;
            async_ld16(&X [(size_t)(blockM + row) * CDIM + k0 + scol], &As[chunk * 512]);
            async_ld16(&Bt[(size_t)(blockN + row) * CDIM + k0 + scol], &Bs[chunk * 512]);
        }
        __syncthreads();

        bf16x8 af[4], bfr[4];
        for (int mi = 0; mi < 4; mi++)
            af[mi] = *(const bf16x8*)&As[(wr * 64 + mi * 16 + l15) * 32 + quad * 8];
        for (int ni = 0; ni < 4; ni++)
            bfr[ni] = *(const bf16x8*)&Bs[(wc * 64 + ni * 16 + l15) * 32 + quad * 8];

        for (int mi = 0; mi < 4; mi++)
            for (int ni = 0; ni < 4; ni++)
                acc[mi][ni] = __builtin_amdgcn_mfma_f32_16x16x32_bf16(
                    af[mi], bfr[ni], acc[mi][ni], 0, 0, 0);
        __syncthreads();
    }

    for (int mi = 0; mi < 4; mi++) {
        int mbase = blockM + wr * 64 + mi * 16 + quad * 4;
        for (int ni = 0; ni < 4; ni++) {
            int n = blockN + wc * 64 + ni * 16 + l15;
            float bval = __bfloat162float(bias[n]);
            for (int r = 0; r < 4; r++)
                Out[(size_t)(mbase + r) * CDIM + n] = acc[mi][ni][r] + bval;
        }
    }
}

// ---------------------------------------------------------------------------
// Flash attention, causal.  64-q tiles, 4 waves, P-in-registers,
// global_load_lds staging with XOR-swizzled reads, and DOUBLE-BUFFERED LDS
// (T3-minimal 2-phase): per iteration, STAGE(buf^1, kt+1) is issued BEFORE
// computing tile kt from buf[cur]; the single end-of-iteration barrier (with
// the compiler's conservative vmcnt(0) drain) then lands AFTER ~600-900 cyc
// of MFMA+exp work, so the staging latency is hidden instead of exposed
// between two barriers (round-5 structure: stage -> drain -> compute had the
// full L2/HBM latency serial with compute; m233's "2-phase stall").
// Barriers also drop from 2 to 1 per key-tile.  LDS 2x16KB = 32KB.
// Swizzle recap: stage dest is linear stride-64 rows; the global SOURCE col
// is inverse-permuted per-lane ((l&7)^(l>>3), valid since each wave-call
// covers exactly 8 rows) and every LDS read XORs col16 with (row&7).
// exp2: v_exp_f32 is natively 2^x; Q is pre-scaled by (1/32)*log2(e) so the
// softmax uses exp2 directly (saves a v_mul per element; softmax invariant).
// ---------------------------------------------------------------------------
__global__ __launch_bounds__(256, 4) void attn_kernel(
    const bf16* __restrict__ Q, const bf16* __restrict__ Kb,
    const bf16* __restrict__ Vt, bf16* __restrict__ Y)
{
    const int bh    = blockIdx.y;
    const int qT    = (int)gridDim.x - 1 - blockIdx.x;   // 0..31, heavy first
    const int qBase = qT * 64;
    const int tid  = threadIdx.x;
    const int lane = tid & 63, wave = tid >> 6;          // wave 0..3
    const int l15 = lane & 15, quad = lane >> 4;

    __shared__ __align__(16) bf16 smem[2 * 2 * 64 * 64];     // 32 KiB, 2 bufs
    // buf b: K at smem + b*8192, V at smem + b*8192 + 4096 (stride-64 rows)

    // Q B-fragments: this wave's 16 q rows
    const size_t qrow = (size_t)bh * TDIM + qBase + wave * 16 + l15;
    const bf16x8 qf0 = *(const bf16x8*)&Q[qrow * DH + quad * 8];
    const bf16x8 qf1 = *(const bf16x8*)&Q[qrow * DH + 32 + quad * 8];

    // O^T accumulators: o[mt][r] -> d = mt*16+quad*4+r, q = l15
    f32x4 o[4];
    for (int mt = 0; mt < 4; mt++) o[mt] = (f32x4){0.f, 0.f, 0.f, 0.f};
    float lsum = 0.f;

    // --- staging geometry: wave w, chunk cc covers rows w*16+cc*8..+7 ------
    // lane l: row = base + (l>>3); since base%8==0, row&7 == l>>3.
    // inverse-swizzled source col16 = (l&7) ^ (l>>3)  (per-lane constant)
    const int srow = (wave << 4) + (lane >> 3);                 // cc=0 row
    const int ssc  = (((lane & 7) ^ (lane >> 3)) << 3);         // elem offset
    const bf16* kSrc0 = Kb + ((size_t)bh * TDIM + srow) * DH + ssc;   // +kt*64*DH, +8*DH
    const bf16* vSrc0 = Vt + ((size_t)bh * DH + srow) * TDIM + ssc;   // +kt*64,    +8*TDIM

    // read-side swizzle constants
    const int swA   = l15 & 7;                         // row&7 for fragment rows
    const int kcol0 = ((quad ^ swA) << 3);             // logical col16=quad
    const int kcol1 = (((4 + quad) ^ swA) << 3);       // logical col16=4+quad
    const int u2    = quad >> 1, intra = ((quad & 1) << 2);

    const int nkt  = qT + 1;
    const int qloc = wave * 16 + l15;    // q offset within this 64-q tile

    // ---- prologue: stage tile 0 into buf 0 --------------------------------
    {
        const bf16* kS = kSrc0;
        const bf16* vS = vSrc0;
        bf16* kD = smem + (wave * 16) * 64;
        bf16* vD = smem + 4096 + (wave * 16) * 64;
        async_ld16(kS,            kD);
        async_ld16(kS + 8 * DH,   kD + 8 * 64);
        async_ld16(vS,            vD);
        async_ld16(vS + 8 * TDIM, vD + 8 * 64);
    }
    __syncthreads();   // vmcnt(0) drain: tile 0 resident

    int cur = 0;
    for (int kt = 0; kt < nkt; kt++) {
        // ---- issue next tile's loads into the other buffer (hidden) -------
        if (kt + 1 < nkt) {
            const bf16* kS = kSrc0 + (size_t)(kt + 1) * 64 * DH;
            const bf16* vS = vSrc0 + (size_t)(kt + 1) * 64;
            bf16* kD = smem + (cur ^ 1) * 8192 + (wave * 16) * 64;
            bf16* vD = smem + (cur ^ 1) * 8192 + 4096 + (wave * 16) * 64;
            async_ld16(kS,            kD);
            async_ld16(kS + 8 * DH,   kD + 8 * 64);
            async_ld16(vS,            vD);
            async_ld16(vS + 8 * TDIM, vD + 8 * 64);
        }

        const bf16* Ks = smem + cur * 8192;
        const bf16* Vs = Ks + 4096;

        const bool diag = (kt == qT);
        for (int nt = 0; nt < 4; nt++) {
            // K A-frag for this 16-key chunk (swizzled cols)
            bf16x8 kf0 = *(const bf16x8*)&Ks[(nt * 16 + l15) * 64 + kcol0];
            bf16x8 kf1 = *(const bf16x8*)&Ks[(nt * 16 + l15) * 64 + kcol1];
            // V A-frags (16x16x16): logical elem col nt*16+quad*4
            bf16x4 vA[4];
            for (int mt = 0; mt < 4; mt++)
                vA[mt] = *(const bf16x4*)&Vs[(mt * 16 + l15) * 64 +
                                             (((nt * 2 + u2) ^ swA) << 3) + intra];

            f32x4 s = (f32x4){0.f, 0.f, 0.f, 0.f};
            s = __builtin_amdgcn_mfma_f32_16x16x32_bf16(kf0, qf0, s, 0, 0, 0);
            s = __builtin_amdgcn_mfma_f32_16x16x32_bf16(kf1, qf1, s, 0, 0, 0);

            bf16x4 pb;
            for (int r = 0; r < 4; r++) {
                float pe = fast_exp2(s[r]);
                if (diag && (nt * 16 + quad * 4 + r > qloc)) pe = 0.f;
                lsum += pe;
                pb[r] = (short)bf16bits(pe);
            }
            for (int mt = 0; mt < 4; mt++)
                o[mt] = mfma_16x16x16_bf16(vA[mt], pb, o[mt]);
        }
        __syncthreads();   // drains kt+1 loads (issued pre-compute) + buf reuse
        cur ^= 1;
    }

    // ---- epilogue: normalize, per-wave LDS transpose, coalesced store ----
    float v = lsum;
    v += __shfl_xor(v, 16, 64);
    v += __shfl_xor(v, 32, 64);
    const float inv = 1.0f / v;

    // o -> LDS wave-private slice [q row][d col], stride 72 over smem scratch
    unsigned short* sm = (unsigned short*)smem;
    for (int mt = 0; mt < 4; mt++) {
        unsigned short pk[4];
        for (int r = 0; r < 4; r++) pk[r] = bf16bits(o[mt][r] * inv);
        *(ushort4*)&sm[(wave * 16 + l15) * 72 + mt * 16 + quad * 4] = *(ushort4*)pk;
    }
    // same-wave readback, coalesced global store
    const int b = bh >> 4, h = bh & 15;
    const int qq = lane >> 2, part = lane & 3;
    const int t = qBase + wave * 16 + qq;
    uint4 c0 = *(const uint4*)&sm[(wave * 16 + qq) * 72 + part * 16];
    uint4 c1 = *(const uint4*)&sm[(wave * 16 + qq) * 72 + part * 16 + 8];
    *(uint4*)&Y[((size_t)b * TDIM + t) * CDIM + h * DH + part * 16]     = c0;
    *(uint4*)&Y[((size_t)b * TDIM + t) * CDIM + h * DH + part * 16 + 8] = c1;
}

// ---------------------------------------------------------------------------
extern "C" void kernel_launch(void* const* d_in, const int* in_sizes, int n_in,
                              void* d_out, int out_size, void* d_ws, size_t ws_size,
                              hipStream_t stream) {
    (void)in_sizes; (void)n_in; (void)out_size; (void)ws_size;

    char* ws = (char*)d_ws;
    const size_t SZ_BHTD = (size_t)BDIM * HDIM * TDIM * DH * sizeof(bf16);  // 16 MiB
    const size_t SZ_W    = (size_t)HDIM * CDIM * DH * sizeof(bf16);         // 2 MiB
    bf16* Qb  = (bf16*)(ws);
    bf16* Kb  = (bf16*)(ws + SZ_BHTD);
    bf16* Vt  = (bf16*)(ws + 2 * SZ_BHTD);
    bf16* Y   = (bf16*)(ws + 3 * SZ_BHTD);
    bf16* WqT = (bf16*)(ws + 4 * SZ_BHTD);
    bf16* WkT = (bf16*)(ws + 4 * SZ_BHTD + SZ_W);
    bf16* WvT = (bf16*)(ws + 4 * SZ_BHTD + 2 * SZ_W);
    bf16* WoT = (bf16*)(ws + 4 * SZ_BHTD + 3 * SZ_W);
    bf16* xC  = (bf16*)(ws + 4 * SZ_BHTD + 4 * SZ_W);                       // 16 MiB
    bf16* bqC = (bf16*)(ws + 5 * SZ_BHTD + 4 * SZ_W);
    bf16* bkC = bqC + 1024;
    bf16* bvC = bqC + 2048;
    bf16* boC = bqC + 3072;
    bf16* Vb  = (bf16*)d_out;   // scratch: V [bh][t][d] lives in d_out until proj_out

    const int nX4 = (BDIM * TDIM * CDIM) / 4;
    convert_x4<<<nX4 / 256, 256, 0, stream>>>((const float4*)d_in[0], (ushort4*)xC, nX4);
    convert_biases<<<16, 256, 0, stream>>>((const float*)d_in[2], (const float*)d_in[4],
                                           (const float*)d_in[6], (const float*)d_in[8], bqC);

    transpose_qkv_kernel<<<dim3(CDIM / 64, 1, 48), 256, 0, stream>>>(
        (const float*)d_in[1], (const float*)d_in[3], (const float*)d_in[5], WqT, WkT, WvT);
    transpose_wo_kernel<<<dim3(CDIM / 64, CDIM / 64), 256, 0, stream>>>(
        (const float*)d_in[7], WoT);

    dim3 gq(CDIM / 128, (BDIM * TDIM) / 128, 3);
    proj_qkv_kernel<<<gq, 256, 0, stream>>>(xC, WqT, WkT, WvT, bqC, bkC, bvC, Qb, Kb, Vb);

    transpose_v_kernel<<<dim3(TDIM / 64, BDIM * HDIM), 256, 0, stream>>>(Vb, Vt);

    attn_kernel<<<dim3(TDIM / 64, BDIM * HDIM), 256, 0, stream>>>(Qb, Kb, Vt, Y);

    proj_out_kernel<<<dim3(CDIM / 128, (BDIM * TDIM) / 128), 256, 0, stream>>>(
        Y, WoT, boC, (float*)d_out);
}